// Round 12
// baseline (271.929 us; speedup 1.0000x reference)
//
#include <hip/hip_runtime.h>
#include <hip/hip_bf16.h>

#define NN 50000
#define NE 600000
#define SLOTS 48  // bucket capacity per node; deg ~ Poisson(12), P(deg>=48) ~ 1e-15/node

typedef unsigned short ushortT;
typedef __attribute__((ext_vector_type(8))) short bf16x8;
typedef __attribute__((ext_vector_type(4))) float f32x4;

__device__ __forceinline__ ushortT f2bfbits(float f) {
    __hip_bfloat16 h = __float2bfloat16(f);  // RNE
    return *reinterpret_cast<ushortT*>(&h);
}

__device__ __forceinline__ float4 unpack_bf4(uint2 p) {
    float4 r;
    r.x = __uint_as_float(p.x << 16);
    r.y = __uint_as_float(p.x & 0xffff0000u);
    r.z = __uint_as_float(p.y << 16);
    r.w = __uint_as_float(p.y & 0xffff0000u);
    return r;
}

// ---------- W prepack into MFMA B-fragment order (device fn) ----------
template <int K, int M>
__device__ __forceinline__ void pack_w_dev(const float* __restrict__ W,
                                           ushortT* __restrict__ Wp, int t) {
    constexpr int KC = K / 32;
    constexpr int CT = M / 16;
    if (t >= CT * KC * 64) return;
    int l = t & 63;
    int q = (t >> 6) % KC;
    int c = t / (64 * KC);
    int m = l & 15, quad = l >> 4;
    alignas(16) ushortT tmp[8];
#pragma unroll
    for (int j = 0; j < 8; ++j)
        tmp[j] = f2bfbits(W[(size_t)(q * 32 + quad * 8 + j) * M + c * 16 + m]);
    *reinterpret_cast<uint4*>(&Wp[(size_t)t * 8]) = *reinterpret_cast<const uint4*>(tmp);
}

// ---------- prep: zero counts + BN sums, pack all three weight matrices ----------
__global__ void __launch_bounds__(256) prep_kernel(const float* __restrict__ W1,
                                                   const float* __restrict__ W2,
                                                   const float* __restrict__ W3,
                                                   ushortT* __restrict__ Wp1,
                                                   ushortT* __restrict__ Wp2,
                                                   ushortT* __restrict__ Wp3,
                                                   int* __restrict__ counts,
                                                   float* __restrict__ sums, int n) {
    int b = blockIdx.x, tid = threadIdx.x;
    if (b < 8) {
        pack_w_dev<128, 128>(W1, Wp1, b * 256 + tid);
    } else if (b < 12) {
        pack_w_dev<128, 64>(W2, Wp2, (b - 8) * 256 + tid);
    } else if (b < 13) {
        pack_w_dev<64, 32>(W3, Wp3, (b - 12) * 256 + tid);
    } else {
        int i = (b - 13) * 256 + tid;
        if (i < n) counts[i] = 0;
        if (b == 13) sums[tid] = 0.f;
    }
}

// ---------- MFMA GEMM core (device fn, no LDS) ----------
// FUSEBN: a' = relu(a*sc[k]+sh[k]) with sc/sh computed from sums/gamma/beta in registers.
// Layouts (HW-verified, guide §3): A[m=lane&15][k=quad*8+j]; B[k][n=lane&15]; D[n=lane&15][m=quad*4+r].
template <typename AT, int K, int M, bool FUSEBN>
__device__ __forceinline__ void gemm_dev(int bid, const AT* __restrict__ A,
                                         const ushortT* __restrict__ Wp,
                                         const float* __restrict__ sums,
                                         const float* __restrict__ gamma,
                                         const float* __restrict__ beta,
                                         ushortT* __restrict__ out, int N) {
    constexpr int KC = K / 32;
    constexpr int CT = M / 16;
    int wave = threadIdx.x >> 6;
    int lane = threadIdx.x & 63;
    int m = lane & 15, quad = lane >> 4;
    int rowbase = bid * 64 + wave * 16;
    int arow = min(rowbase + m, N - 1);  // clamp; stores are masked

    f32x4 acc[CT] = {};
    const float invN = 1.0f / (float)N;

#pragma unroll
    for (int q = 0; q < KC; ++q) {
        int kb = q * 32 + quad * 8;
        float av[8];
        if constexpr (sizeof(AT) == 4) {
            const float* ap = (const float*)A + (size_t)arow * K + kb;
            float4 lo = *reinterpret_cast<const float4*>(ap);
            float4 hi = *reinterpret_cast<const float4*>(ap + 4);
            av[0] = lo.x; av[1] = lo.y; av[2] = lo.z; av[3] = lo.w;
            av[4] = hi.x; av[5] = hi.y; av[6] = hi.z; av[7] = hi.w;
        } else {
            const ushortT* ap = (const ushortT*)A + (size_t)arow * K + kb;
            uint4 p = *reinterpret_cast<const uint4*>(ap);
            float4 lo = unpack_bf4(make_uint2(p.x, p.y));
            float4 hi = unpack_bf4(make_uint2(p.z, p.w));
            av[0] = lo.x; av[1] = lo.y; av[2] = lo.z; av[3] = lo.w;
            av[4] = hi.x; av[5] = hi.y; av[6] = hi.z; av[7] = hi.w;
        }
        if constexpr (FUSEBN) {
#pragma unroll
            for (int j = 0; j < 8; ++j) {
                int k = kb + j;
                float mean = sums[k] * invN;
                float var = fmaf(-mean, mean, sums[K + k] * invN);
                var = var > 0.f ? var : 0.f;
                float sc = gamma[k] * rsqrtf(var + 1e-5f);
                float sh = fmaf(-mean, sc, beta[k]);
                av[j] = fmaxf(fmaf(av[j], sc, sh), 0.f);
            }
        }
        bf16x8 af;
#pragma unroll
        for (int j = 0; j < 8; ++j) af[j] = (short)f2bfbits(av[j]);
#pragma unroll
        for (int c = 0; c < CT; ++c) {
            bf16x8 bf = *reinterpret_cast<const bf16x8*>(
                &Wp[(((size_t)c * KC + q) * 64 + lane) * 8]);
            acc[c] = __builtin_amdgcn_mfma_f32_16x16x32_bf16(af, bf, acc[c], 0, 0, 0);
        }
    }
#pragma unroll
    for (int c = 0; c < CT; ++c) {
#pragma unroll
        for (int r = 0; r < 4; ++r) {
            int row = rowbase + quad * 4 + r;
            if (row < N) out[(size_t)row * M + c * 16 + m] = f2bfbits(acc[c][r]);
        }
    }
}

// ---------- merged launch: bucket_fill blocks [0,FB) + gemm1 blocks [FB,FB+GB) ----------
// Independent work co-scheduled on the CUs: fill is atomic/latency-bound (VALU/VMEM),
// gemm1 is MFMA-bound — per m114 they overlap (time ~ max, not sum).
__global__ void __launch_bounds__(256) fill_gemm1_kernel(
    const int* __restrict__ src, const int* __restrict__ dst, const float* __restrict__ w,
    int* __restrict__ counts, int2* __restrict__ col_sw, int E,
    const float* __restrict__ x, const ushortT* __restrict__ Wp1,
    ushortT* __restrict__ hlin, int N, int FB) {
    if ((int)blockIdx.x < FB) {
        int e = blockIdx.x * 256 + threadIdx.x;
        if (e < E) {
            int d = dst[e];
            int pos = atomicAdd(&counts[d], 1);
            if (pos < SLOTS) col_sw[(size_t)pos * N + d] = make_int2(src[e], __float_as_int(w[e]));
        }
        return;
    }
    gemm_dev<float, 128, 128, false>(blockIdx.x - FB, x, Wp1, nullptr, nullptr, nullptr, hlin, N);
}

// ---------- plain MFMA GEMM kernel (layers 2, 3) ----------
template <typename AT, int K, int M, bool FUSEBN>
__global__ void __launch_bounds__(256) mfma_gemm(const AT* __restrict__ A,
                                                 const ushortT* __restrict__ Wp,
                                                 const float* __restrict__ sums,
                                                 const float* __restrict__ gamma,
                                                 const float* __restrict__ beta,
                                                 ushortT* __restrict__ out, int N) {
    gemm_dev<AT, K, M, FUSEBN>(blockIdx.x, A, Wp, sums, gamma, beta, out, N);
}

// ---------- deg/dinv: dinv[i] = rsqrt(1 + sum of bucket weights) ----------
__global__ void deg_dinv_kernel(const int* __restrict__ counts, const int2* __restrict__ col_sw,
                                float* __restrict__ dinv, int n) {
    int i = blockIdx.x * blockDim.x + threadIdx.x;
    if (i >= n) return;
    int c = min(counts[i], SLOTS);
    float s = 1.0f;
    for (int j = 0; j < c; ++j) s += __int_as_float(col_sw[(size_t)j * n + i].y);
    dinv[i] = rsqrtf(s);
}

// ---------- norm (in-place, coalesced in slot-major): w -> dinv[s]*w*dinv[d] ----------
__global__ void norm_bucket_kernel(const int* __restrict__ counts, int2* __restrict__ col_sw,
                                   const float* __restrict__ dinv, int n) {
    int idx = blockIdx.x * blockDim.x + threadIdx.x;
    if (idx >= n * SLOTS) return;
    int j = idx / n;
    int node = idx - j * n;
    if (j >= min(counts[node], SLOTS)) return;
    int2 sw = col_sw[idx];  // idx == j*n + node
    col_sw[idx].y = __float_as_int(dinv[sw.x] * __int_as_float(sw.y) * dinv[node]);
}

// ---------- fused aggregation: 8 ch/thread, uint4 bf16 gathers, unroll x2, fp32 accum ------
template <int C, bool OUTBF, bool ZERO>
__global__ void __launch_bounds__(256) csr_agg_kernel(const ushortT* __restrict__ hbf,
                                                      const int* __restrict__ counts,
                                                      const int2* __restrict__ col_sw,
                                                      const float* __restrict__ dinv,
                                                      const float* __restrict__ bias,
                                                      void* __restrict__ out,
                                                      float* __restrict__ sums, int N) {
    if (ZERO && blockIdx.x == 0) sums[threadIdx.x] = 0.f;  // re-zero BN accumulators
    constexpr int C8 = C / 8;
    int idx = blockIdx.x * 256 + threadIdx.x;
    if (idx >= N * C8) return;
    int node = idx / C8;
    int c8 = idx - node * C8;
    const uint4* h8 = reinterpret_cast<const uint4*>(hbf);
    int cnt = min(counts[node], SLOTS);
    float di = dinv[node];
    float sl = di * di;
    uint4 hp = h8[idx];
    float4 hlo = unpack_bf4(make_uint2(hp.x, hp.y));
    float4 hhi = unpack_bf4(make_uint2(hp.z, hp.w));
    float4 blo = *reinterpret_cast<const float4*>(&bias[8 * c8]);
    float4 bhi = *reinterpret_cast<const float4*>(&bias[8 * c8 + 4]);
    float4 alo, ahi;
    alo.x = fmaf(sl, hlo.x, blo.x); alo.y = fmaf(sl, hlo.y, blo.y);
    alo.z = fmaf(sl, hlo.z, blo.z); alo.w = fmaf(sl, hlo.w, blo.w);
    ahi.x = fmaf(sl, hhi.x, bhi.x); ahi.y = fmaf(sl, hhi.y, bhi.y);
    ahi.z = fmaf(sl, hhi.z, bhi.z); ahi.w = fmaf(sl, hhi.w, bhi.w);
    const int2* cs = col_sw + node;  // slot-major: slot j at cs[j*N]
    int j = 0;
    for (; j + 2 <= cnt; j += 2) {
        int2 sw0 = cs[(size_t)j * N];
        int2 sw1 = cs[(size_t)(j + 1) * N];
        uint4 p0 = h8[(size_t)sw0.x * C8 + c8];
        uint4 p1 = h8[(size_t)sw1.x * C8 + c8];
        float n0 = __int_as_float(sw0.y);
        float n1 = __int_as_float(sw1.y);
        float4 l0 = unpack_bf4(make_uint2(p0.x, p0.y));
        float4 h0 = unpack_bf4(make_uint2(p0.z, p0.w));
        float4 l1 = unpack_bf4(make_uint2(p1.x, p1.y));
        float4 h1 = unpack_bf4(make_uint2(p1.z, p1.w));
        alo.x = fmaf(n0, l0.x, alo.x); alo.y = fmaf(n0, l0.y, alo.y);
        alo.z = fmaf(n0, l0.z, alo.z); alo.w = fmaf(n0, l0.w, alo.w);
        ahi.x = fmaf(n0, h0.x, ahi.x); ahi.y = fmaf(n0, h0.y, ahi.y);
        ahi.z = fmaf(n0, h0.z, ahi.z); ahi.w = fmaf(n0, h0.w, ahi.w);
        alo.x = fmaf(n1, l1.x, alo.x); alo.y = fmaf(n1, l1.y, alo.y);
        alo.z = fmaf(n1, l1.z, alo.z); alo.w = fmaf(n1, l1.w, alo.w);
        ahi.x = fmaf(n1, h1.x, ahi.x); ahi.y = fmaf(n1, h1.y, ahi.y);
        ahi.z = fmaf(n1, h1.z, ahi.z); ahi.w = fmaf(n1, h1.w, ahi.w);
    }
    if (j < cnt) {
        int2 sw = cs[(size_t)j * N];
        float nrm = __int_as_float(sw.y);
        uint4 p = h8[(size_t)sw.x * C8 + c8];
        float4 lo = unpack_bf4(make_uint2(p.x, p.y));
        float4 hi = unpack_bf4(make_uint2(p.z, p.w));
        alo.x = fmaf(nrm, lo.x, alo.x); alo.y = fmaf(nrm, lo.y, alo.y);
        alo.z = fmaf(nrm, lo.z, alo.z); alo.w = fmaf(nrm, lo.w, alo.w);
        ahi.x = fmaf(nrm, hi.x, ahi.x); ahi.y = fmaf(nrm, hi.y, ahi.y);
        ahi.z = fmaf(nrm, hi.z, ahi.z); ahi.w = fmaf(nrm, hi.w, ahi.w);
    }
    if constexpr (OUTBF) {
        alignas(16) ushortT tmp[8];
        tmp[0] = f2bfbits(alo.x); tmp[1] = f2bfbits(alo.y);
        tmp[2] = f2bfbits(alo.z); tmp[3] = f2bfbits(alo.w);
        tmp[4] = f2bfbits(ahi.x); tmp[5] = f2bfbits(ahi.y);
        tmp[6] = f2bfbits(ahi.z); tmp[7] = f2bfbits(ahi.w);
        reinterpret_cast<uint4*>(out)[idx] = *reinterpret_cast<const uint4*>(tmp);
    } else {
        float4* o4 = reinterpret_cast<float4*>(out);
        o4[idx * 2] = alo;
        o4[idx * 2 + 1] = ahi;
    }
}

// ---------- batchnorm stats on bf16 buffer: LDS tree reduction + few atomics ----------
#define BN_GRID 104
template <int C>
__global__ void __launch_bounds__(256) bn_stats_kernel(const ushortT* __restrict__ hbf,
                                                       float* __restrict__ sums, int N) {
    constexpr int C4 = C / 4;
    constexpr int SPB = 256 / C4;
    __shared__ float4 sm1[256], sm2[256];
    int tid = threadIdx.x;
    int c4 = tid % C4;
    int r0 = blockIdx.x * SPB + tid / C4;
    int stride = gridDim.x * SPB;
    const uint2* h2 = reinterpret_cast<const uint2*>(hbf);
    float4 s = make_float4(0.f, 0.f, 0.f, 0.f);
    float4 s2 = make_float4(0.f, 0.f, 0.f, 0.f);
    for (int r = r0; r < N; r += stride) {
        float4 v = unpack_bf4(h2[(size_t)r * C4 + c4]);
        s.x += v.x; s.y += v.y; s.z += v.z; s.w += v.w;
        s2.x = fmaf(v.x, v.x, s2.x);
        s2.y = fmaf(v.y, v.y, s2.y);
        s2.z = fmaf(v.z, v.z, s2.z);
        s2.w = fmaf(v.w, v.w, s2.w);
    }
    sm1[tid] = s; sm2[tid] = s2;
    __syncthreads();
#pragma unroll
    for (int off = 128; off >= C4; off >>= 1) {
        if (tid < off) {
            float4 a = sm1[tid + off], b = sm2[tid + off];
            float4 u = sm1[tid], v = sm2[tid];
            u.x += a.x; u.y += a.y; u.z += a.z; u.w += a.w;
            v.x += b.x; v.y += b.y; v.z += b.z; v.w += b.w;
            sm1[tid] = u; sm2[tid] = v;
        }
        __syncthreads();
    }
    if (tid < C4) {
        float4 a = sm1[tid], b = sm2[tid];
        unsafeAtomicAdd(&sums[4 * tid + 0], a.x);
        unsafeAtomicAdd(&sums[4 * tid + 1], a.y);
        unsafeAtomicAdd(&sums[4 * tid + 2], a.z);
        unsafeAtomicAdd(&sums[4 * tid + 3], a.w);
        unsafeAtomicAdd(&sums[C + 4 * tid + 0], b.x);
        unsafeAtomicAdd(&sums[C + 4 * tid + 1], b.y);
        unsafeAtomicAdd(&sums[C + 4 * tid + 2], b.z);
        unsafeAtomicAdd(&sums[C + 4 * tid + 3], b.w);
    }
}

// ---------- launcher ----------
extern "C" void kernel_launch(void* const* d_in, const int* in_sizes, int n_in,
                              void* d_out, int out_size, void* d_ws, size_t ws_size,
                              hipStream_t stream) {
    const float* x      = (const float*)d_in[0];
    const int*   src    = (const int*)d_in[1];
    const int*   dst    = (const int*)d_in[2];
    const float* weight = (const float*)d_in[3];
    const float* W1     = (const float*)d_in[4];
    const float* b1     = (const float*)d_in[5];
    const float* gamma1 = (const float*)d_in[6];
    const float* beta1  = (const float*)d_in[7];
    const float* W2     = (const float*)d_in[8];
    const float* b2     = (const float*)d_in[9];
    const float* gamma2 = (const float*)d_in[10];
    const float* beta2  = (const float*)d_in[11];
    const float* W3     = (const float*)d_in[12];
    const float* b3     = (const float*)d_in[13];
    float* out = (float*)d_out;  // [N,32] fp32

    const int N = NN, E = NE;

    char* ws = (char*)d_ws;
    size_t off = 0;
    auto alloc = [&](size_t bytes) {
        size_t r = off;
        off += (bytes + 255) & ~(size_t)255;
        return r;
    };
    float*   dinv    = (float*)(ws + alloc((size_t)N * 4));
    int*     counts  = (int*)(ws + alloc((size_t)N * 4));
    int2*    col_sw  = (int2*)(ws + alloc((size_t)N * SLOTS * 8));   // 19.2 MB, slot-major
    ushortT* hlin_bf = (ushortT*)(ws + alloc((size_t)N * 128 * 2));  // 12.8 MB (reused 3x)
    ushortT* hagg_bf = (ushortT*)(ws + alloc((size_t)N * 128 * 2));  // h1agg; h2agg aliases low half
    ushortT* Wp1     = (ushortT*)(ws + alloc(128 * 128 * 2));
    ushortT* Wp2     = (ushortT*)(ws + alloc(128 * 64 * 2));
    ushortT* Wp3     = (ushortT*)(ws + alloc(64 * 32 * 2));
    float*   sums    = (float*)(ws + alloc(256 * 4));

    dim3 blk(256);
    auto grd = [](long long n) { return dim3((unsigned)((n + 255) / 256)); };
    const int GB = (N + 63) / 64;    // gemm blocks (64 rows/block)
    const int DB = (N + 255) / 256;  // node-wise blocks
    const int FB = (E + 255) / 256;  // fill blocks

    // ---- prep (counts+sums zero, pack W1/W2/W3) ----
    prep_kernel<<<13 + DB, blk, 0, stream>>>(W1, W2, W3, Wp1, Wp2, Wp3, counts, sums, N);

    // ----- merged: bucket_fill || gemm1 (independent, co-scheduled) -----
    ushortT* h1agg = hagg_bf;
    fill_gemm1_kernel<<<FB + GB, blk, 0, stream>>>(src, dst, weight, counts, col_sw, E,
                                                   x, Wp1, hlin_bf, N, FB);
    deg_dinv_kernel<<<DB, blk, 0, stream>>>(counts, col_sw, dinv, N);
    norm_bucket_kernel<<<grd((long long)N * SLOTS), blk, 0, stream>>>(counts, col_sw, dinv, N);

    // ----- layer 1 aggregation + BN stats -----
    csr_agg_kernel<128, true, false><<<grd((long long)N * 16), blk, 0, stream>>>(
        hlin_bf, counts, col_sw, dinv, b1, h1agg, sums, N);
    bn_stats_kernel<128><<<BN_GRID, 256, 0, stream>>>(h1agg, sums, N);

    // ----- layer 2: 128 -> 64 (BN1+ReLU computed in-register from sums) -----
    ushortT* h2agg = hagg_bf;  // aliases h1agg's low half; h1agg dead after gemm2
    mfma_gemm<ushortT, 128, 64, true><<<GB, blk, 0, stream>>>(
        h1agg, Wp2, sums, gamma1, beta1, hlin_bf, N);
    csr_agg_kernel<64, true, true><<<grd((long long)N * 8), blk, 0, stream>>>(
        hlin_bf, counts, col_sw, dinv, b2, h2agg, sums, N);
    bn_stats_kernel<64><<<BN_GRID, 256, 0, stream>>>(h2agg, sums, N);

    // ----- layer 3: 64 -> 32 (BN2+ReLU in-register; no BN after), fp32 out -----
    mfma_gemm<ushortT, 64, 32, true><<<GB, blk, 0, stream>>>(
        h2agg, Wp3, sums, gamma2, beta2, hlin_bf, N);
    csr_agg_kernel<32, false, false><<<grd((long long)N * 4), blk, 0, stream>>>(
        hlin_bf, counts, col_sw, dinv, b3, out, sums, N);
}

// Round 13
// 266.450 us; speedup vs baseline: 1.0206x; 1.0206x over previous
//
#include <hip/hip_runtime.h>
#include <hip/hip_bf16.h>

#define NN 50000
#define NE 600000
#define SLOTS 48  // bucket capacity per node; deg ~ Poisson(12), P(deg>=48) ~ 1e-15/node

typedef unsigned short ushortT;
typedef __attribute__((ext_vector_type(8))) short bf16x8;
typedef __attribute__((ext_vector_type(4))) float f32x4;

__device__ __forceinline__ ushortT f2bfbits(float f) {
    __hip_bfloat16 h = __float2bfloat16(f);  // RNE
    return *reinterpret_cast<ushortT*>(&h);
}

__device__ __forceinline__ float4 unpack_bf4(uint2 p) {
    float4 r;
    r.x = __uint_as_float(p.x << 16);
    r.y = __uint_as_float(p.x & 0xffff0000u);
    r.z = __uint_as_float(p.y << 16);
    r.w = __uint_as_float(p.y & 0xffff0000u);
    return r;
}

// ---------- W prepack into MFMA B-fragment order (device fn) ----------
template <int K, int M>
__device__ __forceinline__ void pack_w_dev(const float* __restrict__ W,
                                           ushortT* __restrict__ Wp, int t) {
    constexpr int KC = K / 32;
    constexpr int CT = M / 16;
    if (t >= CT * KC * 64) return;
    int l = t & 63;
    int q = (t >> 6) % KC;
    int c = t / (64 * KC);
    int m = l & 15, quad = l >> 4;
    alignas(16) ushortT tmp[8];
#pragma unroll
    for (int j = 0; j < 8; ++j)
        tmp[j] = f2bfbits(W[(size_t)(q * 32 + quad * 8 + j) * M + c * 16 + m]);
    *reinterpret_cast<uint4*>(&Wp[(size_t)t * 8]) = *reinterpret_cast<const uint4*>(tmp);
}

// ---------- prep: zero counts + BN sums, pack all three weight matrices ----------
__global__ void __launch_bounds__(256) prep_kernel(const float* __restrict__ W1,
                                                   const float* __restrict__ W2,
                                                   const float* __restrict__ W3,
                                                   ushortT* __restrict__ Wp1,
                                                   ushortT* __restrict__ Wp2,
                                                   ushortT* __restrict__ Wp3,
                                                   int* __restrict__ counts,
                                                   float* __restrict__ sums, int n) {
    int b = blockIdx.x, tid = threadIdx.x;
    if (b < 8) {
        pack_w_dev<128, 128>(W1, Wp1, b * 256 + tid);
    } else if (b < 12) {
        pack_w_dev<128, 64>(W2, Wp2, (b - 8) * 256 + tid);
    } else if (b < 13) {
        pack_w_dev<64, 32>(W3, Wp3, (b - 12) * 256 + tid);
    } else {
        int i = (b - 13) * 256 + tid;
        if (i < n) counts[i] = 0;
        if (b == 13) sums[tid] = 0.f;
    }
}

// ---------- bucket fill: one atomic + one 8B store per edge, slot-major, raw w ----------
__global__ void bucket_fill_kernel(const int* __restrict__ src, const int* __restrict__ dst,
                                   const float* __restrict__ w, int* __restrict__ counts,
                                   int2* __restrict__ col_sw, int E, int n) {
    int e = blockIdx.x * 256 + threadIdx.x;
    if (e < E) {
        int d = dst[e];
        int pos = atomicAdd(&counts[d], 1);
        if (pos < SLOTS) col_sw[(size_t)pos * n + d] = make_int2(src[e], __float_as_int(w[e]));
    }
}

// ---------- deg/dinv: dinv[i] = rsqrt(1 + sum of bucket weights) ----------
__global__ void deg_dinv_kernel(const int* __restrict__ counts, const int2* __restrict__ col_sw,
                                float* __restrict__ dinv, int n) {
    int i = blockIdx.x * 256 + threadIdx.x;
    if (i >= n) return;
    int c = min(counts[i], SLOTS);
    float s = 1.0f;
    for (int j = 0; j < c; ++j) s += __int_as_float(col_sw[(size_t)j * n + i].y);
    dinv[i] = rsqrtf(s);
}

// ---------- MFMA GEMM (no LDS), optional in-register BN affine ----------
// Layouts (HW-verified, guide §3): A[m=lane&15][k=quad*8+j]; B[k][n=lane&15]; D[n=lane&15][m=quad*4+r].
template <typename AT, int K, int M, bool FUSEBN>
__global__ void __launch_bounds__(256) mfma_gemm(const AT* __restrict__ A,
                                                 const ushortT* __restrict__ Wp,
                                                 const float* __restrict__ sums,
                                                 const float* __restrict__ gamma,
                                                 const float* __restrict__ beta,
                                                 ushortT* __restrict__ out, int N) {
    constexpr int KC = K / 32;
    constexpr int CT = M / 16;
    int wave = threadIdx.x >> 6;
    int lane = threadIdx.x & 63;
    int m = lane & 15, quad = lane >> 4;
    int rowbase = blockIdx.x * 64 + wave * 16;
    int arow = min(rowbase + m, N - 1);  // clamp; stores are masked

    f32x4 acc[CT] = {};
    const float invN = 1.0f / (float)N;

#pragma unroll
    for (int q = 0; q < KC; ++q) {
        int kb = q * 32 + quad * 8;
        float av[8];
        if constexpr (sizeof(AT) == 4) {
            const float* ap = (const float*)A + (size_t)arow * K + kb;
            float4 lo = *reinterpret_cast<const float4*>(ap);
            float4 hi = *reinterpret_cast<const float4*>(ap + 4);
            av[0] = lo.x; av[1] = lo.y; av[2] = lo.z; av[3] = lo.w;
            av[4] = hi.x; av[5] = hi.y; av[6] = hi.z; av[7] = hi.w;
        } else {
            const ushortT* ap = (const ushortT*)A + (size_t)arow * K + kb;
            uint4 p = *reinterpret_cast<const uint4*>(ap);
            float4 lo = unpack_bf4(make_uint2(p.x, p.y));
            float4 hi = unpack_bf4(make_uint2(p.z, p.w));
            av[0] = lo.x; av[1] = lo.y; av[2] = lo.z; av[3] = lo.w;
            av[4] = hi.x; av[5] = hi.y; av[6] = hi.z; av[7] = hi.w;
        }
        if constexpr (FUSEBN) {
#pragma unroll
            for (int j = 0; j < 8; ++j) {
                int k = kb + j;
                float mean = sums[k] * invN;
                float var = fmaf(-mean, mean, sums[K + k] * invN);
                var = var > 0.f ? var : 0.f;
                float sc = gamma[k] * rsqrtf(var + 1e-5f);
                float sh = fmaf(-mean, sc, beta[k]);
                av[j] = fmaxf(fmaf(av[j], sc, sh), 0.f);
            }
        }
        bf16x8 af;
#pragma unroll
        for (int j = 0; j < 8; ++j) af[j] = (short)f2bfbits(av[j]);
#pragma unroll
        for (int c = 0; c < CT; ++c) {
            bf16x8 bf = *reinterpret_cast<const bf16x8*>(
                &Wp[(((size_t)c * KC + q) * 64 + lane) * 8]);
            acc[c] = __builtin_amdgcn_mfma_f32_16x16x32_bf16(af, bf, acc[c], 0, 0, 0);
        }
    }
#pragma unroll
    for (int c = 0; c < CT; ++c) {
#pragma unroll
        for (int r = 0; r < 4; ++r) {
            int row = rowbase + quad * 4 + r;
            if (row < N) out[(size_t)row * M + c * 16 + m] = f2bfbits(acc[c][r]);
        }
    }
}

// ---------- fused aggregation: 8 ch/thread, inline norm, unroll x4, fp32 accum ----------
// out[i,c] = b[c] + dinv[i]^2*hlin[i,c] + sum_in (dinv[src]*w*dinv[i])*hlin[src,c]
template <int C, bool OUTBF, bool ZERO>
__global__ void __launch_bounds__(256) csr_agg_kernel(const ushortT* __restrict__ hbf,
                                                      const int* __restrict__ counts,
                                                      const int2* __restrict__ col_sw,
                                                      const float* __restrict__ dinv,
                                                      const float* __restrict__ bias,
                                                      void* __restrict__ out,
                                                      float* __restrict__ sums, int N) {
    if (ZERO && blockIdx.x == 0) sums[threadIdx.x] = 0.f;  // re-zero BN accumulators
    constexpr int C8 = C / 8;
    int idx = blockIdx.x * 256 + threadIdx.x;
    if (idx >= N * C8) return;
    int node = idx / C8;
    int c8 = idx - node * C8;
    const uint4* h8 = reinterpret_cast<const uint4*>(hbf);
    int cnt = min(counts[node], SLOTS);
    float di = dinv[node];
    float sl = di * di;
    uint4 hp = h8[idx];
    float4 hlo = unpack_bf4(make_uint2(hp.x, hp.y));
    float4 hhi = unpack_bf4(make_uint2(hp.z, hp.w));
    float4 blo = *reinterpret_cast<const float4*>(&bias[8 * c8]);
    float4 bhi = *reinterpret_cast<const float4*>(&bias[8 * c8 + 4]);
    float4 alo, ahi;
    alo.x = fmaf(sl, hlo.x, blo.x); alo.y = fmaf(sl, hlo.y, blo.y);
    alo.z = fmaf(sl, hlo.z, blo.z); alo.w = fmaf(sl, hlo.w, blo.w);
    ahi.x = fmaf(sl, hhi.x, bhi.x); ahi.y = fmaf(sl, hhi.y, bhi.y);
    ahi.z = fmaf(sl, hhi.z, bhi.z); ahi.w = fmaf(sl, hhi.w, bhi.w);
    const int2* cs = col_sw + node;  // slot-major: slot j at cs[j*N]

#define ACC_EDGE(SW, DV)                                            \
    {                                                               \
        float nrm = DV * __int_as_float((SW).y) * di;               \
        uint4 p = h8[(size_t)(SW).x * C8 + c8];                     \
        float4 lo = unpack_bf4(make_uint2(p.x, p.y));               \
        float4 hi = unpack_bf4(make_uint2(p.z, p.w));               \
        alo.x = fmaf(nrm, lo.x, alo.x); alo.y = fmaf(nrm, lo.y, alo.y); \
        alo.z = fmaf(nrm, lo.z, alo.z); alo.w = fmaf(nrm, lo.w, alo.w); \
        ahi.x = fmaf(nrm, hi.x, ahi.x); ahi.y = fmaf(nrm, hi.y, ahi.y); \
        ahi.z = fmaf(nrm, hi.z, ahi.z); ahi.w = fmaf(nrm, hi.w, ahi.w); \
    }

    int j = 0;
    for (; j + 4 <= cnt; j += 4) {
        int2 sw0 = cs[(size_t)(j + 0) * N];
        int2 sw1 = cs[(size_t)(j + 1) * N];
        int2 sw2 = cs[(size_t)(j + 2) * N];
        int2 sw3 = cs[(size_t)(j + 3) * N];
        float d0 = dinv[sw0.x], d1 = dinv[sw1.x], d2 = dinv[sw2.x], d3 = dinv[sw3.x];
        ACC_EDGE(sw0, d0);
        ACC_EDGE(sw1, d1);
        ACC_EDGE(sw2, d2);
        ACC_EDGE(sw3, d3);
    }
    for (; j < cnt; ++j) {
        int2 sw = cs[(size_t)j * N];
        float dv = dinv[sw.x];
        ACC_EDGE(sw, dv);
    }
#undef ACC_EDGE

    if constexpr (OUTBF) {
        alignas(16) ushortT tmp[8];
        tmp[0] = f2bfbits(alo.x); tmp[1] = f2bfbits(alo.y);
        tmp[2] = f2bfbits(alo.z); tmp[3] = f2bfbits(alo.w);
        tmp[4] = f2bfbits(ahi.x); tmp[5] = f2bfbits(ahi.y);
        tmp[6] = f2bfbits(ahi.z); tmp[7] = f2bfbits(ahi.w);
        reinterpret_cast<uint4*>(out)[idx] = *reinterpret_cast<const uint4*>(tmp);
    } else {
        float4* o4 = reinterpret_cast<float4*>(out);
        o4[idx * 2] = alo;
        o4[idx * 2 + 1] = ahi;
    }
}

// ---------- batchnorm stats on bf16 buffer: LDS tree reduction + few atomics ----------
#define BN_GRID 104
template <int C>
__global__ void __launch_bounds__(256) bn_stats_kernel(const ushortT* __restrict__ hbf,
                                                       float* __restrict__ sums, int N) {
    constexpr int C4 = C / 4;
    constexpr int SPB = 256 / C4;
    __shared__ float4 sm1[256], sm2[256];
    int tid = threadIdx.x;
    int c4 = tid % C4;
    int r0 = blockIdx.x * SPB + tid / C4;
    int stride = gridDim.x * SPB;
    const uint2* h2 = reinterpret_cast<const uint2*>(hbf);
    float4 s = make_float4(0.f, 0.f, 0.f, 0.f);
    float4 s2 = make_float4(0.f, 0.f, 0.f, 0.f);
    for (int r = r0; r < N; r += stride) {
        float4 v = unpack_bf4(h2[(size_t)r * C4 + c4]);
        s.x += v.x; s.y += v.y; s.z += v.z; s.w += v.w;
        s2.x = fmaf(v.x, v.x, s2.x);
        s2.y = fmaf(v.y, v.y, s2.y);
        s2.z = fmaf(v.z, v.z, s2.z);
        s2.w = fmaf(v.w, v.w, s2.w);
    }
    sm1[tid] = s; sm2[tid] = s2;
    __syncthreads();
#pragma unroll
    for (int off = 128; off >= C4; off >>= 1) {
        if (tid < off) {
            float4 a = sm1[tid + off], b = sm2[tid + off];
            float4 u = sm1[tid], v = sm2[tid];
            u.x += a.x; u.y += a.y; u.z += a.z; u.w += a.w;
            v.x += b.x; v.y += b.y; v.z += b.z; v.w += b.w;
            sm1[tid] = u; sm2[tid] = v;
        }
        __syncthreads();
    }
    if (tid < C4) {
        float4 a = sm1[tid], b = sm2[tid];
        unsafeAtomicAdd(&sums[4 * tid + 0], a.x);
        unsafeAtomicAdd(&sums[4 * tid + 1], a.y);
        unsafeAtomicAdd(&sums[4 * tid + 2], a.z);
        unsafeAtomicAdd(&sums[4 * tid + 3], a.w);
        unsafeAtomicAdd(&sums[C + 4 * tid + 0], b.x);
        unsafeAtomicAdd(&sums[C + 4 * tid + 1], b.y);
        unsafeAtomicAdd(&sums[C + 4 * tid + 2], b.z);
        unsafeAtomicAdd(&sums[C + 4 * tid + 3], b.w);
    }
}

// ---------- launcher ----------
extern "C" void kernel_launch(void* const* d_in, const int* in_sizes, int n_in,
                              void* d_out, int out_size, void* d_ws, size_t ws_size,
                              hipStream_t stream) {
    const float* x      = (const float*)d_in[0];
    const int*   src    = (const int*)d_in[1];
    const int*   dst    = (const int*)d_in[2];
    const float* weight = (const float*)d_in[3];
    const float* W1     = (const float*)d_in[4];
    const float* b1     = (const float*)d_in[5];
    const float* gamma1 = (const float*)d_in[6];
    const float* beta1  = (const float*)d_in[7];
    const float* W2     = (const float*)d_in[8];
    const float* b2     = (const float*)d_in[9];
    const float* gamma2 = (const float*)d_in[10];
    const float* beta2  = (const float*)d_in[11];
    const float* W3     = (const float*)d_in[12];
    const float* b3     = (const float*)d_in[13];
    float* out = (float*)d_out;  // [N,32] fp32

    const int N = NN, E = NE;

    char* ws = (char*)d_ws;
    size_t off = 0;
    auto alloc = [&](size_t bytes) {
        size_t r = off;
        off += (bytes + 255) & ~(size_t)255;
        return r;
    };
    float*   dinv    = (float*)(ws + alloc((size_t)N * 4));
    int*     counts  = (int*)(ws + alloc((size_t)N * 4));
    int2*    col_sw  = (int2*)(ws + alloc((size_t)N * SLOTS * 8));   // 19.2 MB, slot-major, raw w
    ushortT* hlin_bf = (ushortT*)(ws + alloc((size_t)N * 128 * 2));  // 12.8 MB (reused 3x)
    ushortT* hagg_bf = (ushortT*)(ws + alloc((size_t)N * 128 * 2));  // h1agg; h2agg aliases low half
    ushortT* Wp1     = (ushortT*)(ws + alloc(128 * 128 * 2));
    ushortT* Wp2     = (ushortT*)(ws + alloc(128 * 64 * 2));
    ushortT* Wp3     = (ushortT*)(ws + alloc(64 * 32 * 2));
    float*   sums    = (float*)(ws + alloc(256 * 4));

    dim3 blk(256);
    auto grd = [](long long n) { return dim3((unsigned)((n + 255) / 256)); };
    const int GB = (N + 63) / 64;    // gemm blocks (64 rows/block)
    const int DB = (N + 255) / 256;  // node-wise blocks

    // ---- prep (counts+sums zero, pack W1/W2/W3), bucket fill, gemm1, dinv ----
    prep_kernel<<<13 + DB, blk, 0, stream>>>(W1, W2, W3, Wp1, Wp2, Wp3, counts, sums, N);
    bucket_fill_kernel<<<grd(E), blk, 0, stream>>>(src, dst, weight, counts, col_sw, E, N);
    mfma_gemm<float, 128, 128, false><<<GB, blk, 0, stream>>>(
        x, Wp1, nullptr, nullptr, nullptr, hlin_bf, N);
    deg_dinv_kernel<<<DB, blk, 0, stream>>>(counts, col_sw, dinv, N);

    // ----- layer 1 aggregation + BN stats -----
    ushortT* h1agg = hagg_bf;
    csr_agg_kernel<128, true, false><<<grd((long long)N * 16), blk, 0, stream>>>(
        hlin_bf, counts, col_sw, dinv, b1, h1agg, sums, N);
    bn_stats_kernel<128><<<BN_GRID, 256, 0, stream>>>(h1agg, sums, N);

    // ----- layer 2: 128 -> 64 (BN1+ReLU computed in-register from sums) -----
    ushortT* h2agg = hagg_bf;  // aliases h1agg's low half; h1agg dead after gemm2
    mfma_gemm<ushortT, 128, 64, true><<<GB, blk, 0, stream>>>(
        h1agg, Wp2, sums, gamma1, beta1, hlin_bf, N);
    csr_agg_kernel<64, true, true><<<grd((long long)N * 8), blk, 0, stream>>>(
        hlin_bf, counts, col_sw, dinv, b2, h2agg, sums, N);
    bn_stats_kernel<64><<<BN_GRID, 256, 0, stream>>>(h2agg, sums, N);

    // ----- layer 3: 64 -> 32 (BN2+ReLU in-register; no BN after), fp32 out -----
    mfma_gemm<ushortT, 64, 32, true><<<GB, blk, 0, stream>>>(
        h2agg, Wp3, sums, gamma2, beta2, hlin_bf, N);
    csr_agg_kernel<32, false, false><<<grd((long long)N * 4), blk, 0, stream>>>(
        hlin_bf, counts, col_sw, dinv, b3, out, sums, N);
}

// Round 14
// 264.404 us; speedup vs baseline: 1.0285x; 1.0077x over previous
//
#include <hip/hip_runtime.h>
#include <hip/hip_bf16.h>

#define NN 50000
#define NE 600000
#define SLOTS 48  // bucket capacity per node; deg ~ Poisson(12), P(deg>=48) ~ 1e-15/node

typedef unsigned short ushortT;
typedef unsigned int uintT;
typedef __attribute__((ext_vector_type(8))) short bf16x8;
typedef __attribute__((ext_vector_type(4))) float f32x4;

__device__ __forceinline__ ushortT f2bfbits(float f) {
    __hip_bfloat16 h = __float2bfloat16(f);  // RNE
    return *reinterpret_cast<ushortT*>(&h);
}

__device__ __forceinline__ float4 unpack_bf4(uint2 p) {
    float4 r;
    r.x = __uint_as_float(p.x << 16);
    r.y = __uint_as_float(p.x & 0xffff0000u);
    r.z = __uint_as_float(p.y << 16);
    r.w = __uint_as_float(p.y & 0xffff0000u);
    return r;
}

// packed edge record: low 16 bits = src node id (N < 65536), high 16 bits = bf16(w)
__device__ __forceinline__ int esrc(uintT v) { return (int)(v & 0xFFFFu); }
__device__ __forceinline__ float ew(uintT v) { return __uint_as_float(v & 0xFFFF0000u); }

// ---------- W prepack into MFMA B-fragment order (device fn) ----------
template <int K, int M>
__device__ __forceinline__ void pack_w_dev(const float* __restrict__ W,
                                           ushortT* __restrict__ Wp, int t) {
    constexpr int KC = K / 32;
    constexpr int CT = M / 16;
    if (t >= CT * KC * 64) return;
    int l = t & 63;
    int q = (t >> 6) % KC;
    int c = t / (64 * KC);
    int m = l & 15, quad = l >> 4;
    alignas(16) ushortT tmp[8];
#pragma unroll
    for (int j = 0; j < 8; ++j)
        tmp[j] = f2bfbits(W[(size_t)(q * 32 + quad * 8 + j) * M + c * 16 + m]);
    *reinterpret_cast<uint4*>(&Wp[(size_t)t * 8]) = *reinterpret_cast<const uint4*>(tmp);
}

// ---------- prep: zero counts + BN sums, pack all three weight matrices ----------
__global__ void __launch_bounds__(256) prep_kernel(const float* __restrict__ W1,
                                                   const float* __restrict__ W2,
                                                   const float* __restrict__ W3,
                                                   ushortT* __restrict__ Wp1,
                                                   ushortT* __restrict__ Wp2,
                                                   ushortT* __restrict__ Wp3,
                                                   int* __restrict__ counts,
                                                   float* __restrict__ sums, int n) {
    int b = blockIdx.x, tid = threadIdx.x;
    if (b < 8) {
        pack_w_dev<128, 128>(W1, Wp1, b * 256 + tid);
    } else if (b < 12) {
        pack_w_dev<128, 64>(W2, Wp2, (b - 8) * 256 + tid);
    } else if (b < 13) {
        pack_w_dev<64, 32>(W3, Wp3, (b - 12) * 256 + tid);
    } else {
        int i = (b - 13) * 256 + tid;
        if (i < n) counts[i] = 0;
        if (b == 13) sums[tid] = 0.f;
    }
}

// ---------- bucket fill: one atomic + one 4B store per edge, slot-major, packed ----------
__global__ void bucket_fill_kernel(const int* __restrict__ src, const int* __restrict__ dst,
                                   const float* __restrict__ w, int* __restrict__ counts,
                                   uintT* __restrict__ col_sw, int E, int n) {
    int e = blockIdx.x * 256 + threadIdx.x;
    if (e < E) {
        int d = dst[e];
        int pos = atomicAdd(&counts[d], 1);
        if (pos < SLOTS) {
            uintT rec = ((uintT)f2bfbits(w[e]) << 16) | (uintT)src[e];
            col_sw[(size_t)pos * n + d] = rec;
        }
    }
}

// ---------- deg/dinv: dinv[i] = rsqrt(1 + sum of bucket weights) ----------
__global__ void deg_dinv_kernel(const int* __restrict__ counts, const uintT* __restrict__ col_sw,
                                float* __restrict__ dinv, int n) {
    int i = blockIdx.x * 256 + threadIdx.x;
    if (i >= n) return;
    int c = min(counts[i], SLOTS);
    float s = 1.0f;
    for (int j = 0; j < c; ++j) s += ew(col_sw[(size_t)j * n + i]);
    dinv[i] = rsqrtf(s);
}

// ---------- MFMA GEMM (no LDS), optional in-register BN affine ----------
// Layouts (HW-verified, guide §3): A[m=lane&15][k=quad*8+j]; B[k][n=lane&15]; D[n=lane&15][m=quad*4+r].
template <typename AT, int K, int M, bool FUSEBN>
__global__ void __launch_bounds__(256) mfma_gemm(const AT* __restrict__ A,
                                                 const ushortT* __restrict__ Wp,
                                                 const float* __restrict__ sums,
                                                 const float* __restrict__ gamma,
                                                 const float* __restrict__ beta,
                                                 ushortT* __restrict__ out, int N) {
    constexpr int KC = K / 32;
    constexpr int CT = M / 16;
    int wave = threadIdx.x >> 6;
    int lane = threadIdx.x & 63;
    int m = lane & 15, quad = lane >> 4;
    int rowbase = blockIdx.x * 64 + wave * 16;
    int arow = min(rowbase + m, N - 1);  // clamp; stores are masked

    f32x4 acc[CT] = {};
    const float invN = 1.0f / (float)N;

#pragma unroll
    for (int q = 0; q < KC; ++q) {
        int kb = q * 32 + quad * 8;
        float av[8];
        if constexpr (sizeof(AT) == 4) {
            const float* ap = (const float*)A + (size_t)arow * K + kb;
            float4 lo = *reinterpret_cast<const float4*>(ap);
            float4 hi = *reinterpret_cast<const float4*>(ap + 4);
            av[0] = lo.x; av[1] = lo.y; av[2] = lo.z; av[3] = lo.w;
            av[4] = hi.x; av[5] = hi.y; av[6] = hi.z; av[7] = hi.w;
        } else {
            const ushortT* ap = (const ushortT*)A + (size_t)arow * K + kb;
            uint4 p = *reinterpret_cast<const uint4*>(ap);
            float4 lo = unpack_bf4(make_uint2(p.x, p.y));
            float4 hi = unpack_bf4(make_uint2(p.z, p.w));
            av[0] = lo.x; av[1] = lo.y; av[2] = lo.z; av[3] = lo.w;
            av[4] = hi.x; av[5] = hi.y; av[6] = hi.z; av[7] = hi.w;
        }
        if constexpr (FUSEBN) {
#pragma unroll
            for (int j = 0; j < 8; ++j) {
                int k = kb + j;
                float mean = sums[k] * invN;
                float var = fmaf(-mean, mean, sums[K + k] * invN);
                var = var > 0.f ? var : 0.f;
                float sc = gamma[k] * rsqrtf(var + 1e-5f);
                float sh = fmaf(-mean, sc, beta[k]);
                av[j] = fmaxf(fmaf(av[j], sc, sh), 0.f);
            }
        }
        bf16x8 af;
#pragma unroll
        for (int j = 0; j < 8; ++j) af[j] = (short)f2bfbits(av[j]);
#pragma unroll
        for (int c = 0; c < CT; ++c) {
            bf16x8 bf = *reinterpret_cast<const bf16x8*>(
                &Wp[(((size_t)c * KC + q) * 64 + lane) * 8]);
            acc[c] = __builtin_amdgcn_mfma_f32_16x16x32_bf16(af, bf, acc[c], 0, 0, 0);
        }
    }
#pragma unroll
    for (int c = 0; c < CT; ++c) {
#pragma unroll
        for (int r = 0; r < 4; ++r) {
            int row = rowbase + quad * 4 + r;
            if (row < N) out[(size_t)row * M + c * 16 + m] = f2bfbits(acc[c][r]);
        }
    }
}

// ---------- fused aggregation: 8 ch/thread, packed edges, inline norm, unroll x4 ----------
// out[i,c] = b[c] + dinv[i]^2*hlin[i,c] + sum_in (dinv[src]*w*dinv[i])*hlin[src,c]
template <int C, bool OUTBF, bool ZERO>
__global__ void __launch_bounds__(256) csr_agg_kernel(const ushortT* __restrict__ hbf,
                                                      const int* __restrict__ counts,
                                                      const uintT* __restrict__ col_sw,
                                                      const float* __restrict__ dinv,
                                                      const float* __restrict__ bias,
                                                      void* __restrict__ out,
                                                      float* __restrict__ sums, int N) {
    if (ZERO && blockIdx.x == 0) sums[threadIdx.x] = 0.f;  // re-zero BN accumulators
    constexpr int C8 = C / 8;
    int idx = blockIdx.x * 256 + threadIdx.x;
    if (idx >= N * C8) return;
    int node = idx / C8;
    int c8 = idx - node * C8;
    const uint4* h8 = reinterpret_cast<const uint4*>(hbf);
    int cnt = min(counts[node], SLOTS);
    float di = dinv[node];
    float sl = di * di;
    uint4 hp = h8[idx];
    float4 hlo = unpack_bf4(make_uint2(hp.x, hp.y));
    float4 hhi = unpack_bf4(make_uint2(hp.z, hp.w));
    float4 blo = *reinterpret_cast<const float4*>(&bias[8 * c8]);
    float4 bhi = *reinterpret_cast<const float4*>(&bias[8 * c8 + 4]);
    float4 alo, ahi;
    alo.x = fmaf(sl, hlo.x, blo.x); alo.y = fmaf(sl, hlo.y, blo.y);
    alo.z = fmaf(sl, hlo.z, blo.z); alo.w = fmaf(sl, hlo.w, blo.w);
    ahi.x = fmaf(sl, hhi.x, bhi.x); ahi.y = fmaf(sl, hhi.y, bhi.y);
    ahi.z = fmaf(sl, hhi.z, bhi.z); ahi.w = fmaf(sl, hhi.w, bhi.w);
    const uintT* cs = col_sw + node;  // slot-major: slot j at cs[j*N]

#define ACC_EDGE(SW, DV)                                                \
    {                                                                   \
        float nrm = DV * ew(SW) * di;                                   \
        uint4 p = h8[(size_t)esrc(SW) * C8 + c8];                       \
        float4 lo = unpack_bf4(make_uint2(p.x, p.y));                   \
        float4 hi = unpack_bf4(make_uint2(p.z, p.w));                   \
        alo.x = fmaf(nrm, lo.x, alo.x); alo.y = fmaf(nrm, lo.y, alo.y); \
        alo.z = fmaf(nrm, lo.z, alo.z); alo.w = fmaf(nrm, lo.w, alo.w); \
        ahi.x = fmaf(nrm, hi.x, ahi.x); ahi.y = fmaf(nrm, hi.y, ahi.y); \
        ahi.z = fmaf(nrm, hi.z, ahi.z); ahi.w = fmaf(nrm, hi.w, ahi.w); \
    }

    int j = 0;
    for (; j + 4 <= cnt; j += 4) {
        uintT sw0 = cs[(size_t)(j + 0) * N];
        uintT sw1 = cs[(size_t)(j + 1) * N];
        uintT sw2 = cs[(size_t)(j + 2) * N];
        uintT sw3 = cs[(size_t)(j + 3) * N];
        float d0 = dinv[esrc(sw0)], d1 = dinv[esrc(sw1)];
        float d2 = dinv[esrc(sw2)], d3 = dinv[esrc(sw3)];
        ACC_EDGE(sw0, d0);
        ACC_EDGE(sw1, d1);
        ACC_EDGE(sw2, d2);
        ACC_EDGE(sw3, d3);
    }
    for (; j < cnt; ++j) {
        uintT sw = cs[(size_t)j * N];
        float dv = dinv[esrc(sw)];
        ACC_EDGE(sw, dv);
    }
#undef ACC_EDGE

    if constexpr (OUTBF) {
        alignas(16) ushortT tmp[8];
        tmp[0] = f2bfbits(alo.x); tmp[1] = f2bfbits(alo.y);
        tmp[2] = f2bfbits(alo.z); tmp[3] = f2bfbits(alo.w);
        tmp[4] = f2bfbits(ahi.x); tmp[5] = f2bfbits(ahi.y);
        tmp[6] = f2bfbits(ahi.z); tmp[7] = f2bfbits(ahi.w);
        reinterpret_cast<uint4*>(out)[idx] = *reinterpret_cast<const uint4*>(tmp);
    } else {
        float4* o4 = reinterpret_cast<float4*>(out);
        o4[idx * 2] = alo;
        o4[idx * 2 + 1] = ahi;
    }
}

// ---------- batchnorm stats on bf16 buffer: LDS tree reduction + few atomics ----------
#define BN_GRID 104
template <int C>
__global__ void __launch_bounds__(256) bn_stats_kernel(const ushortT* __restrict__ hbf,
                                                       float* __restrict__ sums, int N) {
    constexpr int C4 = C / 4;
    constexpr int SPB = 256 / C4;
    __shared__ float4 sm1[256], sm2[256];
    int tid = threadIdx.x;
    int c4 = tid % C4;
    int r0 = blockIdx.x * SPB + tid / C4;
    int stride = gridDim.x * SPB;
    const uint2* h2 = reinterpret_cast<const uint2*>(hbf);
    float4 s = make_float4(0.f, 0.f, 0.f, 0.f);
    float4 s2 = make_float4(0.f, 0.f, 0.f, 0.f);
    for (int r = r0; r < N; r += stride) {
        float4 v = unpack_bf4(h2[(size_t)r * C4 + c4]);
        s.x += v.x; s.y += v.y; s.z += v.z; s.w += v.w;
        s2.x = fmaf(v.x, v.x, s2.x);
        s2.y = fmaf(v.y, v.y, s2.y);
        s2.z = fmaf(v.z, v.z, s2.z);
        s2.w = fmaf(v.w, v.w, s2.w);
    }
    sm1[tid] = s; sm2[tid] = s2;
    __syncthreads();
#pragma unroll
    for (int off = 128; off >= C4; off >>= 1) {
        if (tid < off) {
            float4 a = sm1[tid + off], b = sm2[tid + off];
            float4 u = sm1[tid], v = sm2[tid];
            u.x += a.x; u.y += a.y; u.z += a.z; u.w += a.w;
            v.x += b.x; v.y += b.y; v.z += b.z; v.w += b.w;
            sm1[tid] = u; sm2[tid] = v;
        }
        __syncthreads();
    }
    if (tid < C4) {
        float4 a = sm1[tid], b = sm2[tid];
        unsafeAtomicAdd(&sums[4 * tid + 0], a.x);
        unsafeAtomicAdd(&sums[4 * tid + 1], a.y);
        unsafeAtomicAdd(&sums[4 * tid + 2], a.z);
        unsafeAtomicAdd(&sums[4 * tid + 3], a.w);
        unsafeAtomicAdd(&sums[C + 4 * tid + 0], b.x);
        unsafeAtomicAdd(&sums[C + 4 * tid + 1], b.y);
        unsafeAtomicAdd(&sums[C + 4 * tid + 2], b.z);
        unsafeAtomicAdd(&sums[C + 4 * tid + 3], b.w);
    }
}

// ---------- launcher ----------
extern "C" void kernel_launch(void* const* d_in, const int* in_sizes, int n_in,
                              void* d_out, int out_size, void* d_ws, size_t ws_size,
                              hipStream_t stream) {
    const float* x      = (const float*)d_in[0];
    const int*   src    = (const int*)d_in[1];
    const int*   dst    = (const int*)d_in[2];
    const float* weight = (const float*)d_in[3];
    const float* W1     = (const float*)d_in[4];
    const float* b1     = (const float*)d_in[5];
    const float* gamma1 = (const float*)d_in[6];
    const float* beta1  = (const float*)d_in[7];
    const float* W2     = (const float*)d_in[8];
    const float* b2     = (const float*)d_in[9];
    const float* gamma2 = (const float*)d_in[10];
    const float* beta2  = (const float*)d_in[11];
    const float* W3     = (const float*)d_in[12];
    const float* b3     = (const float*)d_in[13];
    float* out = (float*)d_out;  // [N,32] fp32

    const int N = NN, E = NE;

    char* ws = (char*)d_ws;
    size_t off = 0;
    auto alloc = [&](size_t bytes) {
        size_t r = off;
        off += (bytes + 255) & ~(size_t)255;
        return r;
    };
    float*   dinv    = (float*)(ws + alloc((size_t)N * 4));
    int*     counts  = (int*)(ws + alloc((size_t)N * 4));
    uintT*   col_sw  = (uintT*)(ws + alloc((size_t)N * SLOTS * 4));  // 9.6 MB, slot-major, packed
    ushortT* hlin_bf = (ushortT*)(ws + alloc((size_t)N * 128 * 2));  // 12.8 MB (reused 3x)
    ushortT* hagg_bf = (ushortT*)(ws + alloc((size_t)N * 128 * 2));  // h1agg; h2agg aliases low half
    ushortT* Wp1     = (ushortT*)(ws + alloc(128 * 128 * 2));
    ushortT* Wp2     = (ushortT*)(ws + alloc(128 * 64 * 2));
    ushortT* Wp3     = (ushortT*)(ws + alloc(64 * 32 * 2));
    float*   sums    = (float*)(ws + alloc(256 * 4));

    dim3 blk(256);
    auto grd = [](long long n) { return dim3((unsigned)((n + 255) / 256)); };
    const int GB = (N + 63) / 64;    // gemm blocks (64 rows/block)
    const int DB = (N + 255) / 256;  // node-wise blocks

    // ---- prep (counts+sums zero, pack W1/W2/W3), bucket fill, gemm1, dinv ----
    prep_kernel<<<13 + DB, blk, 0, stream>>>(W1, W2, W3, Wp1, Wp2, Wp3, counts, sums, N);
    bucket_fill_kernel<<<grd(E), blk, 0, stream>>>(src, dst, weight, counts, col_sw, E, N);
    mfma_gemm<float, 128, 128, false><<<GB, blk, 0, stream>>>(
        x, Wp1, nullptr, nullptr, nullptr, hlin_bf, N);
    deg_dinv_kernel<<<DB, blk, 0, stream>>>(counts, col_sw, dinv, N);

    // ----- layer 1 aggregation + BN stats -----
    ushortT* h1agg = hagg_bf;
    csr_agg_kernel<128, true, false><<<grd((long long)N * 16), blk, 0, stream>>>(
        hlin_bf, counts, col_sw, dinv, b1, h1agg, sums, N);
    bn_stats_kernel<128><<<BN_GRID, 256, 0, stream>>>(h1agg, sums, N);

    // ----- layer 2: 128 -> 64 (BN1+ReLU computed in-register from sums) -----
    ushortT* h2agg = hagg_bf;  // aliases h1agg's low half; h1agg dead after gemm2
    mfma_gemm<ushortT, 128, 64, true><<<GB, blk, 0, stream>>>(
        h1agg, Wp2, sums, gamma1, beta1, hlin_bf, N);
    csr_agg_kernel<64, true, true><<<grd((long long)N * 8), blk, 0, stream>>>(
        hlin_bf, counts, col_sw, dinv, b2, h2agg, sums, N);
    bn_stats_kernel<64><<<BN_GRID, 256, 0, stream>>>(h2agg, sums, N);

    // ----- layer 3: 64 -> 32 (BN2+ReLU in-register; no BN after), fp32 out -----
    mfma_gemm<ushortT, 64, 32, true><<<GB, blk, 0, stream>>>(
        h2agg, Wp3, sums, gamma2, beta2, hlin_bf, N);
    csr_agg_kernel<32, false, false><<<grd((long long)N * 4), blk, 0, stream>>>(
        hlin_bf, counts, col_sw, dinv, b3, out, sums, N);
}

// Round 16
// 257.189 us; speedup vs baseline: 1.0573x; 1.0281x over previous
//
#include <hip/hip_runtime.h>
#include <hip/hip_bf16.h>

#define NN 50000
#define NE 600000
#define SLOTS 48  // bucket capacity per node; deg ~ Poisson(12), P(deg>=48) ~ 1e-15/node

typedef unsigned short ushortT;
typedef unsigned int uintT;
typedef __attribute__((ext_vector_type(8))) short bf16x8;
typedef __attribute__((ext_vector_type(4))) float f32x4;

__device__ __forceinline__ ushortT f2bfbits(float f) {
    __hip_bfloat16 h = __float2bfloat16(f);  // RNE
    return *reinterpret_cast<ushortT*>(&h);
}

__device__ __forceinline__ float4 unpack_bf4(uint2 p) {
    float4 r;
    r.x = __uint_as_float(p.x << 16);
    r.y = __uint_as_float(p.x & 0xffff0000u);
    r.z = __uint_as_float(p.y << 16);
    r.w = __uint_as_float(p.y & 0xffff0000u);
    return r;
}

// packed edge record: low 16 = src id (N < 65536), high 16 = bf16(w)
__device__ __forceinline__ int esrc(uintT v) { return (int)(v & 0xFFFFu); }
__device__ __forceinline__ float ew(uintT v) { return __uint_as_float(v & 0xFFFF0000u); }

// ---------- W prepack into MFMA B-fragment order (device fn) ----------
template <int K, int M>
__device__ __forceinline__ void pack_w_dev(const float* __restrict__ W,
                                           ushortT* __restrict__ Wp, int t) {
    constexpr int KC = K / 32;
    constexpr int CT = M / 16;
    if (t >= CT * KC * 64) return;
    int l = t & 63;
    int q = (t >> 6) % KC;
    int c = t / (64 * KC);
    int m = l & 15, quad = l >> 4;
    alignas(16) ushortT tmp[8];
#pragma unroll
    for (int j = 0; j < 8; ++j)
        tmp[j] = f2bfbits(W[(size_t)(q * 32 + quad * 8 + j) * M + c * 16 + m]);
    *reinterpret_cast<uint4*>(&Wp[(size_t)t * 8]) = *reinterpret_cast<const uint4*>(tmp);
}

// ---------- prep: zero counts + BN sums, pack all three weight matrices ----------
__global__ void __launch_bounds__(256) prep_kernel(const float* __restrict__ W1,
                                                   const float* __restrict__ W2,
                                                   const float* __restrict__ W3,
                                                   ushortT* __restrict__ Wp1,
                                                   ushortT* __restrict__ Wp2,
                                                   ushortT* __restrict__ Wp3,
                                                   int* __restrict__ counts,
                                                   float* __restrict__ sums, int n) {
    int b = blockIdx.x, tid = threadIdx.x;
    if (b < 8) {
        pack_w_dev<128, 128>(W1, Wp1, b * 256 + tid);
    } else if (b < 12) {
        pack_w_dev<128, 64>(W2, Wp2, (b - 8) * 256 + tid);
    } else if (b < 13) {
        pack_w_dev<64, 32>(W3, Wp3, (b - 12) * 256 + tid);
    } else {
        int i = (b - 13) * 256 + tid;
        if (i < n) counts[i] = 0;
        if (b == 13) sums[tid] = 0.f;
    }
}

// ---------- MFMA GEMM core (device fn, no LDS), optional in-register BN affine ----------
// Layouts (HW-verified, guide §3): A[m=lane&15][k=quad*8+j]; B[k][n=lane&15]; D[n=lane&15][m=quad*4+r].
template <typename AT, int K, int M, bool FUSEBN>
__device__ __forceinline__ void gemm_dev(int bid, const AT* __restrict__ A,
                                         const ushortT* __restrict__ Wp,
                                         const float* __restrict__ sums,
                                         const float* __restrict__ gamma,
                                         const float* __restrict__ beta,
                                         ushortT* __restrict__ out, int N) {
    constexpr int KC = K / 32;
    constexpr int CT = M / 16;
    int wave = threadIdx.x >> 6;
    int lane = threadIdx.x & 63;
    int m = lane & 15, quad = lane >> 4;
    int rowbase = bid * 64 + wave * 16;
    int arow = min(rowbase + m, N - 1);  // clamp; stores are masked

    f32x4 acc[CT] = {};
    const float invN = 1.0f / (float)N;

#pragma unroll
    for (int q = 0; q < KC; ++q) {
        int kb = q * 32 + quad * 8;
        float av[8];
        if constexpr (sizeof(AT) == 4) {
            const float* ap = (const float*)A + (size_t)arow * K + kb;
            float4 lo = *reinterpret_cast<const float4*>(ap);
            float4 hi = *reinterpret_cast<const float4*>(ap + 4);
            av[0] = lo.x; av[1] = lo.y; av[2] = lo.z; av[3] = lo.w;
            av[4] = hi.x; av[5] = hi.y; av[6] = hi.z; av[7] = hi.w;
        } else {
            const ushortT* ap = (const ushortT*)A + (size_t)arow * K + kb;
            uint4 p = *reinterpret_cast<const uint4*>(ap);
            float4 lo = unpack_bf4(make_uint2(p.x, p.y));
            float4 hi = unpack_bf4(make_uint2(p.z, p.w));
            av[0] = lo.x; av[1] = lo.y; av[2] = lo.z; av[3] = lo.w;
            av[4] = hi.x; av[5] = hi.y; av[6] = hi.z; av[7] = hi.w;
        }
        if constexpr (FUSEBN) {
#pragma unroll
            for (int j = 0; j < 8; ++j) {
                int k = kb + j;
                float mean = sums[k] * invN;
                float var = fmaf(-mean, mean, sums[K + k] * invN);
                var = var > 0.f ? var : 0.f;
                float sc = gamma[k] * rsqrtf(var + 1e-5f);
                float sh = fmaf(-mean, sc, beta[k]);
                av[j] = fmaxf(fmaf(av[j], sc, sh), 0.f);
            }
        }
        bf16x8 af;
#pragma unroll
        for (int j = 0; j < 8; ++j) af[j] = (short)f2bfbits(av[j]);
#pragma unroll
        for (int c = 0; c < CT; ++c) {
            bf16x8 bf = *reinterpret_cast<const bf16x8*>(
                &Wp[(((size_t)c * KC + q) * 64 + lane) * 8]);
            acc[c] = __builtin_amdgcn_mfma_f32_16x16x32_bf16(af, bf, acc[c], 0, 0, 0);
        }
    }
#pragma unroll
    for (int c = 0; c < CT; ++c) {
#pragma unroll
        for (int r = 0; r < 4; ++r) {
            int row = rowbase + quad * 4 + r;
            if (row < N) out[(size_t)row * M + c * 16 + m] = f2bfbits(acc[c][r]);
        }
    }
}

// ---------- merged: gemm1 blocks FIRST [0,GB), fill blocks after [GB,GB+FB) ----------
// In-order block dispatch makes gemm resident at t=0 with fill backfilling — true
// co-residency (round-12 failed with fill-first: it drained before gemm got resident).
__global__ void __launch_bounds__(256) gemm1_fill_kernel(
    const float* __restrict__ x, const ushortT* __restrict__ Wp1,
    ushortT* __restrict__ hlin,
    const int* __restrict__ src, const int* __restrict__ dst, const float* __restrict__ w,
    int* __restrict__ counts, uintT* __restrict__ col_sw, int E, int N, int GB) {
    if ((int)blockIdx.x < GB) {
        gemm_dev<float, 128, 128, false>(blockIdx.x, x, Wp1, nullptr, nullptr, nullptr, hlin, N);
        return;
    }
    int e = ((int)blockIdx.x - GB) * 256 + threadIdx.x;
    if (e < E) {
        int d = dst[e];
        int pos = atomicAdd(&counts[d], 1);
        if (pos < SLOTS) {
            uintT rec = ((uintT)f2bfbits(w[e]) << 16) | (uintT)src[e];
            col_sw[(size_t)pos * N + d] = rec;
        }
    }
}

// ---------- plain MFMA GEMM kernel (layers 2, 3) ----------
template <typename AT, int K, int M, bool FUSEBN>
__global__ void __launch_bounds__(256) mfma_gemm(const AT* __restrict__ A,
                                                 const ushortT* __restrict__ Wp,
                                                 const float* __restrict__ sums,
                                                 const float* __restrict__ gamma,
                                                 const float* __restrict__ beta,
                                                 ushortT* __restrict__ out, int N) {
    gemm_dev<AT, K, M, FUSEBN>(blockIdx.x, A, Wp, sums, gamma, beta, out, N);
}

// ---------- deg/dinv: dinv[i] = rsqrt(1 + sum of bucket weights) ----------
__global__ void deg_dinv_kernel(const int* __restrict__ counts, const uintT* __restrict__ col_sw,
                                float* __restrict__ dinv, int n) {
    int i = blockIdx.x * 256 + threadIdx.x;
    if (i >= n) return;
    int c = min(counts[i], SLOTS);
    float s = 1.0f;
    for (int j = 0; j < c; ++j) s += ew(col_sw[(size_t)j * n + i]);
    dinv[i] = rsqrtf(s);
}

// ---------- fused aggregation: 8 ch/thread, packed edges, inline norm, unroll x4 ----------
// out[i,c] = b[c] + dinv[i]^2*hlin[i,c] + sum_in (dinv[src]*w*dinv[i])*hlin[src,c]
template <int C, bool OUTBF, bool ZERO>
__global__ void __launch_bounds__(256) csr_agg_kernel(const ushortT* __restrict__ hbf,
                                                      const int* __restrict__ counts,
                                                      const uintT* __restrict__ col_sw,
                                                      const float* __restrict__ dinv,
                                                      const float* __restrict__ bias,
                                                      void* __restrict__ out,
                                                      float* __restrict__ sums, int N) {
    if (ZERO && blockIdx.x == 0) sums[threadIdx.x] = 0.f;  // re-zero BN accumulators
    constexpr int C8 = C / 8;
    int idx = blockIdx.x * 256 + threadIdx.x;
    if (idx >= N * C8) return;
    int node = idx / C8;
    int c8 = idx - node * C8;
    const uint4* h8 = reinterpret_cast<const uint4*>(hbf);
    int cnt = min(counts[node], SLOTS);
    float di = dinv[node];
    float sl = di * di;
    uint4 hp = h8[idx];
    float4 hlo = unpack_bf4(make_uint2(hp.x, hp.y));
    float4 hhi = unpack_bf4(make_uint2(hp.z, hp.w));
    float4 blo = *reinterpret_cast<const float4*>(&bias[8 * c8]);
    float4 bhi = *reinterpret_cast<const float4*>(&bias[8 * c8 + 4]);
    float4 alo, ahi;
    alo.x = fmaf(sl, hlo.x, blo.x); alo.y = fmaf(sl, hlo.y, blo.y);
    alo.z = fmaf(sl, hlo.z, blo.z); alo.w = fmaf(sl, hlo.w, blo.w);
    ahi.x = fmaf(sl, hhi.x, bhi.x); ahi.y = fmaf(sl, hhi.y, bhi.y);
    ahi.z = fmaf(sl, hhi.z, bhi.z); ahi.w = fmaf(sl, hhi.w, bhi.w);
    const uintT* cs = col_sw + node;  // slot-major: slot j at cs[j*N]

#define ACC_EDGE(SW, DV)                                                \
    {                                                                   \
        float nrm = DV * ew(SW) * di;                                   \
        uint4 p = h8[(size_t)esrc(SW) * C8 + c8];                       \
        float4 lo = unpack_bf4(make_uint2(p.x, p.y));                   \
        float4 hi = unpack_bf4(make_uint2(p.z, p.w));                   \
        alo.x = fmaf(nrm, lo.x, alo.x); alo.y = fmaf(nrm, lo.y, alo.y); \
        alo.z = fmaf(nrm, lo.z, alo.z); alo.w = fmaf(nrm, lo.w, alo.w); \
        ahi.x = fmaf(nrm, hi.x, ahi.x); ahi.y = fmaf(nrm, hi.y, ahi.y); \
        ahi.z = fmaf(nrm, hi.z, ahi.z); ahi.w = fmaf(nrm, hi.w, ahi.w); \
    }

    int j = 0;
    for (; j + 4 <= cnt; j += 4) {
        uintT sw0 = cs[(size_t)(j + 0) * N];
        uintT sw1 = cs[(size_t)(j + 1) * N];
        uintT sw2 = cs[(size_t)(j + 2) * N];
        uintT sw3 = cs[(size_t)(j + 3) * N];
        float d0 = dinv[esrc(sw0)], d1 = dinv[esrc(sw1)];
        float d2 = dinv[esrc(sw2)], d3 = dinv[esrc(sw3)];
        ACC_EDGE(sw0, d0);
        ACC_EDGE(sw1, d1);
        ACC_EDGE(sw2, d2);
        ACC_EDGE(sw3, d3);
    }
    for (; j < cnt; ++j) {
        uintT sw = cs[(size_t)j * N];
        float dv = dinv[esrc(sw)];
        ACC_EDGE(sw, dv);
    }
#undef ACC_EDGE

    if constexpr (OUTBF) {
        alignas(16) ushortT tmp[8];
        tmp[0] = f2bfbits(alo.x); tmp[1] = f2bfbits(alo.y);
        tmp[2] = f2bfbits(alo.z); tmp[3] = f2bfbits(alo.w);
        tmp[4] = f2bfbits(ahi.x); tmp[5] = f2bfbits(ahi.y);
        tmp[6] = f2bfbits(ahi.z); tmp[7] = f2bfbits(ahi.w);
        reinterpret_cast<uint4*>(out)[idx] = *reinterpret_cast<const uint4*>(tmp);
    } else {
        float4* o4 = reinterpret_cast<float4*>(out);
        o4[idx * 2] = alo;
        o4[idx * 2 + 1] = ahi;
    }
}

// ---------- batchnorm stats on bf16 buffer: LDS tree reduction + few atomics ----------
#define BN_GRID 104
template <int C>
__global__ void __launch_bounds__(256) bn_stats_kernel(const ushortT* __restrict__ hbf,
                                                       float* __restrict__ sums, int N) {
    constexpr int C4 = C / 4;
    constexpr int SPB = 256 / C4;
    __shared__ float4 sm1[256], sm2[256];
    int tid = threadIdx.x;
    int c4 = tid % C4;
    int r0 = blockIdx.x * SPB + tid / C4;
    int stride = gridDim.x * SPB;
    const uint2* h2 = reinterpret_cast<const uint2*>(hbf);
    float4 s = make_float4(0.f, 0.f, 0.f, 0.f);
    float4 s2 = make_float4(0.f, 0.f, 0.f, 0.f);
    for (int r = r0; r < N; r += stride) {
        float4 v = unpack_bf4(h2[(size_t)r * C4 + c4]);
        s.x += v.x; s.y += v.y; s.z += v.z; s.w += v.w;
        s2.x = fmaf(v.x, v.x, s2.x);
        s2.y = fmaf(v.y, v.y, s2.y);
        s2.z = fmaf(v.z, v.z, s2.z);
        s2.w = fmaf(v.w, v.w, s2.w);
    }
    sm1[tid] = s; sm2[tid] = s2;
    __syncthreads();
#pragma unroll
    for (int off = 128; off >= C4; off >>= 1) {
        if (tid < off) {
            float4 a = sm1[tid + off], b = sm2[tid + off];
            float4 u = sm1[tid], v = sm2[tid];
            u.x += a.x; u.y += a.y; u.z += a.z; u.w += a.w;
            v.x += b.x; v.y += b.y; v.z += b.z; v.w += b.w;
            sm1[tid] = u; sm2[tid] = v;
        }
        __syncthreads();
    }
    if (tid < C4) {
        float4 a = sm1[tid], b = sm2[tid];
        unsafeAtomicAdd(&sums[4 * tid + 0], a.x);
        unsafeAtomicAdd(&sums[4 * tid + 1], a.y);
        unsafeAtomicAdd(&sums[4 * tid + 2], a.z);
        unsafeAtomicAdd(&sums[4 * tid + 3], a.w);
        unsafeAtomicAdd(&sums[C + 4 * tid + 0], b.x);
        unsafeAtomicAdd(&sums[C + 4 * tid + 1], b.y);
        unsafeAtomicAdd(&sums[C + 4 * tid + 2], b.z);
        unsafeAtomicAdd(&sums[C + 4 * tid + 3], b.w);
    }
}

// ---------- launcher ----------
extern "C" void kernel_launch(void* const* d_in, const int* in_sizes, int n_in,
                              void* d_out, int out_size, void* d_ws, size_t ws_size,
                              hipStream_t stream) {
    const float* x      = (const float*)d_in[0];
    const int*   src    = (const int*)d_in[1];
    const int*   dst    = (const int*)d_in[2];
    const float* weight = (const float*)d_in[3];
    const float* W1     = (const float*)d_in[4];
    const float* b1     = (const float*)d_in[5];
    const float* gamma1 = (const float*)d_in[6];
    const float* beta1  = (const float*)d_in[7];
    const float* W2     = (const float*)d_in[8];
    const float* b2     = (const float*)d_in[9];
    const float* gamma2 = (const float*)d_in[10];
    const float* beta2  = (const float*)d_in[11];
    const float* W3     = (const float*)d_in[12];
    const float* b3     = (const float*)d_in[13];
    float* out = (float*)d_out;  // [N,32] fp32

    const int N = NN, E = NE;

    char* ws = (char*)d_ws;
    size_t off = 0;
    auto alloc = [&](size_t bytes) {
        size_t r = off;
        off += (bytes + 255) & ~(size_t)255;
        return r;
    };
    float*   dinv    = (float*)(ws + alloc((size_t)N * 4));
    int*     counts  = (int*)(ws + alloc((size_t)N * 4));
    uintT*   col_sw  = (uintT*)(ws + alloc((size_t)N * SLOTS * 4));  // 9.6 MB, slot-major, packed
    ushortT* hlin_bf = (ushortT*)(ws + alloc((size_t)N * 128 * 2));  // 12.8 MB (reused 3x)
    ushortT* hagg_bf = (ushortT*)(ws + alloc((size_t)N * 128 * 2));  // h1agg; h2agg aliases low half
    ushortT* Wp1     = (ushortT*)(ws + alloc(128 * 128 * 2));
    ushortT* Wp2     = (ushortT*)(ws + alloc(128 * 64 * 2));
    ushortT* Wp3     = (ushortT*)(ws + alloc(64 * 32 * 2));
    float*   sums    = (float*)(ws + alloc(256 * 4));

    dim3 blk(256);
    auto grd = [](long long n) { return dim3((unsigned)((n + 255) / 256)); };
    const int GB = (N + 63) / 64;    // gemm blocks (64 rows/block)
    const int DB = (N + 255) / 256;  // node-wise blocks
    const int FB = (E + 255) / 256;  // fill blocks

    // ---- prep (counts+sums zero, pack W1/W2/W3) ----
    prep_kernel<<<13 + DB, blk, 0, stream>>>(W1, W2, W3, Wp1, Wp2, Wp3, counts, sums, N);

    // ----- merged: gemm1 blocks first, fill blocks backfill (true co-residency) -----
    gemm1_fill_kernel<<<GB + FB, blk, 0, stream>>>(x, Wp1, hlin_bf,
                                                   src, dst, weight, counts, col_sw, E, N, GB);
    deg_dinv_kernel<<<DB, blk, 0, stream>>>(counts, col_sw, dinv, N);

    // ----- layer 1 aggregation + BN stats -----
    ushortT* h1agg = hagg_bf;
    csr_agg_kernel<128, true, false><<<grd((long long)N * 16), blk, 0, stream>>>(
        hlin_bf, counts, col_sw, dinv, b1, h1agg, sums, N);
    bn_stats_kernel<128><<<BN_GRID, 256, 0, stream>>>(h1agg, sums, N);

    // ----- layer 2: 128 -> 64 (BN1+ReLU computed in-register from sums) -----
    ushortT* h2agg = hagg_bf;  // aliases h1agg's low half; h1agg dead after gemm2
    mfma_gemm<ushortT, 128, 64, true><<<GB, blk, 0, stream>>>(
        h1agg, Wp2, sums, gamma1, beta1, hlin_bf, N);
    csr_agg_kernel<64, true, true><<<grd((long long)N * 8), blk, 0, stream>>>(
        hlin_bf, counts, col_sw, dinv, b2, h2agg, sums, N);
    bn_stats_kernel<64><<<BN_GRID, 256, 0, stream>>>(h2agg, sums, N);

    // ----- layer 3: 64 -> 32 (BN2+ReLU in-register; no BN after), fp32 out -----
    mfma_gemm<ushortT, 64, 32, true><<<GB, blk, 0, stream>>>(
        h2agg, Wp3, sums, gamma2, beta2, hlin_bf, N);
    csr_agg_kernel<32, false, false><<<grd((long long)N * 4), blk, 0, stream>>>(
        hlin_bf, counts, col_sw, dinv, b3, out, sums, N);
}